// Round 5
// baseline (858.121 us; speedup 1.0000x reference)
//
#include <hip/hip_runtime.h>
#include <math.h>

#define NTOK 16384
#define HDIM 2048
#define NEXP 64
#define KK   32
#define TAU  5e-5f

// ws layout (4-byte units):
// [0..64)            inv_nc (f32)
// [64..128)          counts (i32)
// [128..192)         nflag + pad (i32)
// [192..16576)       route  (i32)
// [16576..32960)     flags  (i32)
// [32960..164032)    sums   (f32, 64x2048)     total ~656 KB

__global__ __launch_bounds__(256)
void zero_kernel(float* p, int n) {
  int i = blockIdx.x * 256 + threadIdx.x;
  if (i < n) p[i] = 0.0f;
}

__device__ __forceinline__ float block_reduce_sum(float v, float* red) {
  #pragma unroll
  for (int o = 32; o > 0; o >>= 1) v += __shfl_down(v, o, 64);
  int lane = threadIdx.x & 63;
  int wid  = threadIdx.x >> 6;
  if (lane == 0) red[wid] = v;
  __syncthreads();
  float s = red[0] + red[1] + red[2] + red[3];
  __syncthreads();
  return s;
}

__global__ __launch_bounds__(256)
void cnorm_kernel(const float* __restrict__ c, float* __restrict__ inv_nc) {
  __shared__ float red[4];
  int e = blockIdx.x;
  float ss = 0.f;
  #pragma unroll
  for (int j = 0; j < 8; ++j) {
    float v = c[e * HDIM + threadIdx.x + j * 256];
    ss += v * v;
  }
  float tot = block_reduce_sum(ss, red);
  if (threadIdx.x == 0) inv_nc[e] = 1.0f / fmaxf(sqrtf(tot), 1e-12f);
}

// 64 tokens/block, 256 threads = 4 waves. Wave w -> experts [16w,16w+16), lane -> token.
__global__ __launch_bounds__(256)
void router_kernel(const float* __restrict__ x, const float* __restrict__ c,
                   const float* __restrict__ inv_nc, float* __restrict__ out,
                   int* __restrict__ route, int* __restrict__ nflag,
                   int* __restrict__ flags) {
  __shared__ __align__(16) float xs[64][36];
  __shared__ float lgs[64][67];

  const int tid  = threadIdx.x;
  const int lane = tid & 63;
  const int w    = tid >> 6;
  const int t0   = blockIdx.x * 64;
  const int e0   = __builtin_amdgcn_readfirstlane(w * 16);
  const float* cb = c + (size_t)e0 * HDIM;

  const int st = tid >> 3;
  const int sk = (tid & 7) * 4;

  float acc[16];
  #pragma unroll
  for (int e = 0; e < 16; ++e) acc[e] = 0.f;
  float nacc = 0.f;

  float4 p0 = *(const float4*)&x[(size_t)(t0 + st)      * HDIM + sk];
  float4 p1 = *(const float4*)&x[(size_t)(t0 + st + 32) * HDIM + sk];

  for (int k0 = 0; k0 < HDIM; k0 += KK) {
    __syncthreads();
    *(float4*)&xs[st][sk]      = p0;
    *(float4*)&xs[st + 32][sk] = p1;
    __syncthreads();
    const int kn = k0 + KK;
    if (kn < HDIM) {
      p0 = *(const float4*)&x[(size_t)(t0 + st)      * HDIM + kn + sk];
      p1 = *(const float4*)&x[(size_t)(t0 + st + 32) * HDIM + kn + sk];
    }
    float a[KK];
    #pragma unroll
    for (int j = 0; j < KK; j += 4) {
      float4 v = *(const float4*)&xs[lane][j];
      a[j] = v.x; a[j + 1] = v.y; a[j + 2] = v.z; a[j + 3] = v.w;
    }
    if (w == 0) {
      #pragma unroll
      for (int j = 0; j < KK; ++j) nacc += a[j] * a[j];
    }
    #pragma unroll
    for (int e = 0; e < 16; ++e) {
      const float* br = cb + (size_t)e * HDIM + k0;
      #pragma unroll
      for (int j = 0; j < KK; j += 4) {
        float4 bv = *(const float4*)&br[j];
        acc[e] += a[j] * bv.x;
        acc[e] += a[j + 1] * bv.y;
        acc[e] += a[j + 2] * bv.z;
        acc[e] += a[j + 3] * bv.w;
      }
    }
  }

  #pragma unroll
  for (int e = 0; e < 16; ++e)
    lgs[lane][e0 + e] = acc[e] * inv_nc[e0 + e];
  __syncthreads();

  if (w == 0) {
    const float inv_nx = 1.0f / fmaxf(sqrtf(nacc), 1e-12f);
    float m1 = -1e30f, m2 = -1e30f, m3 = -1e30f;
    int i1 = 0, i2 = 0;
    for (int e = 0; e < NEXP; ++e) {
      float l = lgs[lane][e] * inv_nx;
      if (l > m1)      { m3 = m2; m2 = m1; i2 = i1; m1 = l; i1 = e; }
      else if (l > m2) { m3 = m2; m2 = l; i2 = e; }
      else if (l > m3) { m3 = l; }
    }
    float Z = 0.f;
    for (int e = 0; e < NEXP; ++e)
      Z += expf(lgs[lane][e] * inv_nx - m1);
    const float p1w = 1.0f / Z;
    const float p2w = expf(m2 - m1) / Z;
    const float s   = p1w + p2w + 1e-9f;
    const int tg = t0 + lane;
    out[tg * 2 + 0] = (float)i1;
    out[tg * 2 + 1] = (float)i2;
    out[2 * NTOK + tg * 2 + 0] = p1w / s;
    out[2 * NTOK + tg * 2 + 1] = p2w / s;
    route[tg] = i1;
    if ((m1 - m2) < TAU || (m2 - m3) < TAU) {
      int idx = atomicAdd(nflag, 1);
      flags[idx] = tg;
    }
  }
}

// numpy-fidelity refine: 1 wave per flagged token, lane = expert.
// Emulates: fp32 norms -> fp32 normalized vectors -> exact dot -> fp32 logits ->
// fp32 exp (correctly rounded) + numpy 8-way pairwise fp32 sum -> fp32 probs ->
// top-2 by strict fp32 > scanning ascending index (exact ties -> lower index,
// matching argsort(-p, kind='stable') / lax.top_k semantics).
__global__ __launch_bounds__(64)
void refine_np_kernel(const float* __restrict__ x, const float* __restrict__ c,
                      float* __restrict__ out, int* __restrict__ route,
                      const int* __restrict__ nflag, const int* __restrict__ flags) {
  __shared__ float lf[NEXP];
  const int e = threadIdx.x;   // 0..63: expert
  const int n = *nflag;
  for (int j = blockIdx.x; j < n; j += gridDim.x) {
    const int t = flags[j];
    const float* xr = x + (size_t)t * HDIM;
    const float* cr = c + (size_t)e * HDIM;
    // pass 1: norms in fp64, rounded to fp32 (np materializes fp32 norms)
    double xn = 0.0, cn = 0.0;
    for (int k = 0; k < HDIM; ++k) {
      double xv = (double)xr[k];
      double cv = (double)cr[k];
      xn += xv * xv;
      cn += cv * cv;
    }
    const float nx32 = (float)fmax(sqrt(xn), 1e-12);
    const float nc32 = (float)fmax(sqrt(cn), 1e-12);
    // pass 2: dot of fp32-rounded normalized vectors (np materializes reps_n,
    // centers_n as fp32 arrays), accumulated exactly in fp64
    double d = 0.0;
    for (int k = 0; k < HDIM; ++k) {
      float a = (float)((double)xr[k] / (double)nx32);
      float b = (float)((double)cr[k] / (double)nc32);
      d += (double)a * (double)b;
    }
    lf[e] = (float)d;    // fp32 logit (temp = 1.0 exact)
    __syncthreads();
    if (e == 0) {
      float m32 = lf[0];
      for (int ee = 1; ee < NEXP; ++ee) m32 = fmaxf(m32, lf[ee]);
      float ex[NEXP];
      for (int ee = 0; ee < NEXP; ++ee)
        ex[ee] = (float)exp((double)(lf[ee] - m32));   // correctly-rounded exp32
      // numpy pairwise sum, n=64: 8 accumulators, 8-way unrolled
      float r[8];
      #pragma unroll
      for (int q = 0; q < 8; ++q) r[q] = ex[q];
      for (int i = 8; i < NEXP; i += 8)
        #pragma unroll
        for (int q = 0; q < 8; ++q) r[q] += ex[i + q];
      const float Z = ((r[0] + r[1]) + (r[2] + r[3])) + ((r[4] + r[5]) + (r[6] + r[7]));
      // top-2 on fp32 probs: strict > scanning ascending -> exact ties keep lower index
      float p1 = -1.f, p2 = -1.f;
      int i1 = 0, i2 = 0;
      for (int ee = 0; ee < NEXP; ++ee) {
        float p = ex[ee] / Z;
        if (p > p1)      { p2 = p1; i2 = i1; p1 = p; i1 = ee; }
        else if (p > p2) { p2 = p; i2 = ee; }
      }
      const float s = (p1 + p2) + 1e-9f;
      out[t * 2 + 0] = (float)i1;
      out[t * 2 + 1] = (float)i2;
      out[2 * NTOK + t * 2 + 0] = p1 / s;
      out[2 * NTOK + t * 2 + 1] = p2 / s;
      route[t] = i1;
    }
    __syncthreads();
  }
}

// 8 h-chunks x 32 token-groups (512 tokens each). Also builds counts (hc==0 blocks).
__global__ __launch_bounds__(256)
void segsum_kernel(const float* __restrict__ x, const int* __restrict__ route,
                   float* __restrict__ sums, int* __restrict__ counts) {
  __shared__ float ls[NEXP * 256];
  __shared__ int lcnt[NEXP];
  const int tid = threadIdx.x;
  const int hc  = blockIdx.x & 7;
  const int tg  = blockIdx.x >> 3;
  const int hb  = hc * 256;
  for (int i = tid; i < NEXP * 256; i += 256) ls[i] = 0.f;
  if (tid < NEXP) lcnt[tid] = 0;
  __syncthreads();
  const int t0 = tg * 512;
  #pragma unroll 4
  for (int i = 0; i < 512; ++i) {
    int e = route[t0 + i];
    float v = x[(size_t)(t0 + i) * HDIM + hb + tid];
    ls[e * 256 + tid] += v;
    if (hc == 0 && tid == 0) lcnt[e]++;
  }
  __syncthreads();
  for (int e = 0; e < NEXP; ++e)
    atomicAdd(&sums[e * HDIM + hb + tid], ls[e * 256 + tid]);
  if (hc == 0 && tid < NEXP && lcnt[tid] > 0) atomicAdd(&counts[tid], lcnt[tid]);
}

__global__ __launch_bounds__(256)
void finalize_kernel(const float* __restrict__ c, const float* __restrict__ sums,
                     const int* __restrict__ counts, float* __restrict__ out) {
  __shared__ float red[4];
  const int e = blockIdx.x;
  const int tid = threadIdx.x;
  const float cnt = (float)counts[e];
  const float minv = 1.0f / (cnt + 1e-6f);
  float u[8], cv[8];
  float ss = 0.f;
  #pragma unroll
  for (int j = 0; j < 8; ++j) {
    int h = tid + j * 256;
    cv[j] = c[e * HDIM + h];
    float mean = sums[e * HDIM + h] * minv;
    u[j] = 0.9f * cv[j] + 0.1f * mean;
    ss += u[j] * u[j];
  }
  float tot = block_reduce_sum(ss, red);
  float sc = 1.0f / fmaxf(sqrtf(tot), 1e-12f);
  const bool nz = cnt > 0.f;
  #pragma unroll
  for (int j = 0; j < 8; ++j) {
    int h = tid + j * 256;
    out[4 * NTOK + e * HDIM + h] = nz ? u[j] * sc : cv[j];
  }
}

extern "C" void kernel_launch(void* const* d_in, const int* in_sizes, int n_in,
                              void* d_out, int out_size, void* d_ws, size_t ws_size,
                              hipStream_t stream) {
  const float* x = (const float*)d_in[0];
  const float* c = (const float*)d_in[1];
  float* out = (float*)d_out;
  float* ws = (float*)d_ws;

  float* inv_nc = ws;
  int*   counts = (int*)(ws + 64);
  int*   nflag  = (int*)(ws + 128);
  int*   route  = (int*)(ws + 192);
  int*   flags  = (int*)(ws + 16576);
  float* sums   = ws + 32960;

  zero_kernel<<<1, 256, 0, stream>>>(ws + 64, 128);          // counts + nflag
  zero_kernel<<<512, 256, 0, stream>>>(sums, 131072);
  cnorm_kernel<<<NEXP, 256, 0, stream>>>(c, inv_nc);
  router_kernel<<<NTOK / 64, 256, 0, stream>>>(x, c, inv_nc, out, route, nflag, flags);
  refine_np_kernel<<<1024, 64, 0, stream>>>(x, c, out, route, nflag, flags);
  segsum_kernel<<<256, 256, 0, stream>>>(x, route, sums, counts);
  finalize_kernel<<<NEXP, 256, 0, stream>>>(c, sums, counts, out);
}

// Round 7
// 604.116 us; speedup vs baseline: 1.4205x; 1.4205x over previous
//
#include <hip/hip_runtime.h>
#include <math.h>

#define NTOK 16384
#define HDIM 2048
#define NEXP 64
#define KK   32
#define TAU  5e-5f
#define LGT  16384   // logits row stride (tokens), layout [e][t]

// ws layout (4-byte units):
// [0..64)              inv_nc (f32)
// [64..128)            counts (i32)
// [128..192)           nflag + pad (i32)
// [192..16576)         route  (i32)
// [16576..32960)       flags  (i32)
// [32960..164032)      sums   (f32, 64x2048)
// [164032..180416)     xnorm2 (f32, 16384)
// [180416..1228992)    logits (f32, 64x16384)    total ~4.9 MB

__global__ __launch_bounds__(256)
void zero_kernel(float* p, int n) {
  int i = blockIdx.x * 256 + threadIdx.x;
  if (i < n) p[i] = 0.0f;
}

__device__ __forceinline__ float block_reduce_sum(float v, float* red) {
  #pragma unroll
  for (int o = 32; o > 0; o >>= 1) v += __shfl_down(v, o, 64);
  int lane = threadIdx.x & 63;
  int wid  = threadIdx.x >> 6;
  if (lane == 0) red[wid] = v;
  __syncthreads();
  float s = red[0] + red[1] + red[2] + red[3];
  __syncthreads();
  return s;
}

__global__ __launch_bounds__(256)
void cnorm_kernel(const float* __restrict__ c, float* __restrict__ inv_nc) {
  __shared__ float red[4];
  int e = blockIdx.x;
  float ss = 0.f;
  #pragma unroll
  for (int j = 0; j < 8; ++j) {
    float v = c[e * HDIM + threadIdx.x + j * 256];
    ss += v * v;
  }
  float tot = block_reduce_sum(ss, red);
  if (threadIdx.x == 0) inv_nc[e] = 1.0f / fmaxf(sqrtf(tot), 1e-12f);
}

// K-split GEMM: block = 128 tokens x 64 experts x 512 K. grid = 128 mtiles x 4 ksplits.
// Thread tile: 4 experts x 8 tokens. Partial logits atomic-added to logits[e][t].
__global__ __launch_bounds__(256)
void gemm_kernel(const float* __restrict__ x, const float* __restrict__ c,
                 float* __restrict__ logits, float* __restrict__ xnorm2) {
  __shared__ __align__(16) float xs[KK][132];  // [k][token]; 4224 floats, reused as epilogue tile
  __shared__ __align__(16) float cs[KK][68];   // [k][expert]

  const int tid = threadIdx.x;
  const int mt  = blockIdx.x >> 2;
  const int ks  = blockIdx.x & 3;
  const int t0  = mt * 128;
  const int kb  = ks * 512;
  const int tx  = tid & 15;          // expert group
  const int ty  = tid >> 4;          // token group
  const int r0  = ty * 8;
  const int e0t = tx * 4;
  // staging coords
  const int sr = tid >> 1;           // token row 0..127
  const int sq = (tid & 1) * 16;     // covers k sq..sq+16 (4 float4)
  const int er = tid >> 2;           // expert row 0..63
  const int eq = (tid & 3) * 8;      // covers k eq..eq+8 (2 float4)

  const float* xrow = x + (size_t)(t0 + sr) * HDIM + kb + sq;
  const float* crow = c + (size_t)er * HDIM + kb + eq;

  float4 xp[4], cp[2];
  #pragma unroll
  for (int i = 0; i < 4; ++i) xp[i] = *(const float4*)(xrow + 4 * i);
  #pragma unroll
  for (int i = 0; i < 2; ++i) cp[i] = *(const float4*)(crow + 4 * i);

  float acc[4][8];
  #pragma unroll
  for (int j = 0; j < 4; ++j)
    #pragma unroll
    for (int i = 0; i < 8; ++i) acc[j][i] = 0.f;
  float nacc = 0.f;

  for (int it = 0; it < 16; ++it) {
    __syncthreads();
    #pragma unroll
    for (int i = 0; i < 4; ++i) {
      xs[sq + 4*i + 0][sr] = xp[i].x; xs[sq + 4*i + 1][sr] = xp[i].y;
      xs[sq + 4*i + 2][sr] = xp[i].z; xs[sq + 4*i + 3][sr] = xp[i].w;
      nacc += xp[i].x*xp[i].x + xp[i].y*xp[i].y + xp[i].z*xp[i].z + xp[i].w*xp[i].w;
    }
    #pragma unroll
    for (int i = 0; i < 2; ++i) {
      cs[eq + 4*i + 0][er] = cp[i].x; cs[eq + 4*i + 1][er] = cp[i].y;
      cs[eq + 4*i + 2][er] = cp[i].z; cs[eq + 4*i + 3][er] = cp[i].w;
    }
    __syncthreads();
    if (it < 15) {
      const float* xn = xrow + (it + 1) * KK;
      const float* cn = crow + (it + 1) * KK;
      #pragma unroll
      for (int i = 0; i < 4; ++i) xp[i] = *(const float4*)(xn + 4 * i);
      #pragma unroll
      for (int i = 0; i < 2; ++i) cp[i] = *(const float4*)(cn + 4 * i);
    }
    #pragma unroll
    for (int k = 0; k < KK; ++k) {
      float4 a0 = *(const float4*)&xs[k][r0];
      float4 a1 = *(const float4*)&xs[k][r0 + 4];
      float4 b  = *(const float4*)&cs[k][e0t];
      acc[0][0] += b.x*a0.x; acc[0][1] += b.x*a0.y; acc[0][2] += b.x*a0.z; acc[0][3] += b.x*a0.w;
      acc[0][4] += b.x*a1.x; acc[0][5] += b.x*a1.y; acc[0][6] += b.x*a1.z; acc[0][7] += b.x*a1.w;
      acc[1][0] += b.y*a0.x; acc[1][1] += b.y*a0.y; acc[1][2] += b.y*a0.z; acc[1][3] += b.y*a0.w;
      acc[1][4] += b.y*a1.x; acc[1][5] += b.y*a1.y; acc[1][6] += b.y*a1.z; acc[1][7] += b.y*a1.w;
      acc[2][0] += b.z*a0.x; acc[2][1] += b.z*a0.y; acc[2][2] += b.z*a0.z; acc[2][3] += b.z*a0.w;
      acc[2][4] += b.z*a1.x; acc[2][5] += b.z*a1.y; acc[2][6] += b.z*a1.z; acc[2][7] += b.z*a1.w;
      acc[3][0] += b.w*a0.x; acc[3][1] += b.w*a0.y; acc[3][2] += b.w*a0.z; acc[3][3] += b.w*a0.w;
      acc[3][4] += b.w*a1.x; acc[3][5] += b.w*a1.y; acc[3][6] += b.w*a1.z; acc[3][7] += b.w*a1.w;
    }
  }

  // per-token partial ||x||^2 over this K-chunk (two threads per token, disjoint k)
  atomicAdd(&xnorm2[t0 + sr], nacc);

  // epilogue: transpose 64x128 block tile through LDS -> coalesced atomics.
  // REUSE xs (4224 floats >= 4096 needed). cs (2176) was the R6 OOB bug.
  float* lt = &xs[0][0];
  #pragma unroll
  for (int eh = 0; eh < 2; ++eh) {
    __syncthreads();
    if ((tx >> 3) == eh) {
      const int exl = (tx & 7) * 4;
      #pragma unroll
      for (int j = 0; j < 4; ++j)
        #pragma unroll
        for (int i = 0; i < 8; ++i)
          lt[(exl + j) * 128 + r0 + i] = acc[j][i];
    }
    __syncthreads();
    #pragma unroll
    for (int n = 0; n < 16; ++n) {
      const int f = tid + n * 256;          // 0..4095
      const int e = (f >> 7) + eh * 32;
      const int t = f & 127;
      atomicAdd(&logits[(size_t)e * LGT + t0 + t], lt[f]);
    }
  }
}

// softmax / top-2 / flag. Thread = token. logits layout [e][t] -> coalesced reads.
__global__ __launch_bounds__(256)
void softmax_kernel(const float* __restrict__ logits, const float* __restrict__ xnorm2,
                    const float* __restrict__ inv_nc, float* __restrict__ out,
                    int* __restrict__ route, int* __restrict__ nflag,
                    int* __restrict__ flags) {
  __shared__ float snc[NEXP];
  const int tid = threadIdx.x;
  if (tid < NEXP) snc[tid] = inv_nc[tid];
  __syncthreads();
  const int t = blockIdx.x * 256 + tid;
  const float inv_nx = 1.0f / fmaxf(sqrtf(xnorm2[t]), 1e-12f);
  float lv[NEXP];
  #pragma unroll
  for (int e = 0; e < NEXP; ++e)
    lv[e] = logits[(size_t)e * LGT + t] * snc[e] * inv_nx;
  float m1 = -1e30f, m2 = -1e30f, m3 = -1e30f;
  int i1 = 0, i2 = 0;
  #pragma unroll
  for (int e = 0; e < NEXP; ++e) {
    float l = lv[e];
    if (l > m1)      { m3 = m2; m2 = m1; i2 = i1; m1 = l; i1 = e; }
    else if (l > m2) { m3 = m2; m2 = l; i2 = e; }
    else if (l > m3) { m3 = l; }
  }
  float Z = 0.f;
  #pragma unroll
  for (int e = 0; e < NEXP; ++e) Z += expf(lv[e] - m1);
  const float p1w = 1.0f / Z;
  const float p2w = expf(m2 - m1) / Z;
  const float s   = p1w + p2w + 1e-9f;
  out[t * 2 + 0] = (float)i1;
  out[t * 2 + 1] = (float)i2;
  out[2 * NTOK + t * 2 + 0] = p1w / s;
  out[2 * NTOK + t * 2 + 1] = p2w / s;
  route[t] = i1;
  if ((m1 - m2) < TAU || (m2 - m3) < TAU) {
    int idx = atomicAdd(nflag, 1);
    flags[idx] = t;
  }
}

// numpy-fidelity refine (identical decision pipeline to the R5 version that passed).
__global__ __launch_bounds__(64)
void refine_np_kernel(const float* __restrict__ x, const float* __restrict__ c,
                      float* __restrict__ out, int* __restrict__ route,
                      const int* __restrict__ nflag, const int* __restrict__ flags) {
  __shared__ float lf[NEXP];
  const int e = threadIdx.x;
  const int n = *nflag;
  for (int j = blockIdx.x; j < n; j += gridDim.x) {
    const int t = flags[j];
    const float* xr = x + (size_t)t * HDIM;
    const float* cr = c + (size_t)e * HDIM;
    double xn = 0.0, cn = 0.0;
    for (int k = 0; k < HDIM; ++k) {
      double xv = (double)xr[k];
      double cv = (double)cr[k];
      xn += xv * xv;
      cn += cv * cv;
    }
    const float nx32 = (float)fmax(sqrt(xn), 1e-12);
    const float nc32 = (float)fmax(sqrt(cn), 1e-12);
    double d = 0.0;
    for (int k = 0; k < HDIM; ++k) {
      float a = (float)((double)xr[k] / (double)nx32);
      float b = (float)((double)cr[k] / (double)nc32);
      d += (double)a * (double)b;
    }
    lf[e] = (float)d;
    __syncthreads();
    if (e == 0) {
      float m32 = lf[0];
      for (int ee = 1; ee < NEXP; ++ee) m32 = fmaxf(m32, lf[ee]);
      float ex[NEXP];
      for (int ee = 0; ee < NEXP; ++ee)
        ex[ee] = (float)exp((double)(lf[ee] - m32));
      float r[8];
      #pragma unroll
      for (int q = 0; q < 8; ++q) r[q] = ex[q];
      for (int i = 8; i < NEXP; i += 8)
        #pragma unroll
        for (int q = 0; q < 8; ++q) r[q] += ex[i + q];
      const float Z = ((r[0] + r[1]) + (r[2] + r[3])) + ((r[4] + r[5]) + (r[6] + r[7]));
      float p1 = -1.f, p2 = -1.f;
      int i1 = 0, i2 = 0;
      for (int ee = 0; ee < NEXP; ++ee) {
        float p = ex[ee] / Z;
        if (p > p1)      { p2 = p1; i2 = i1; p1 = p; i1 = ee; }
        else if (p > p2) { p2 = p; i2 = ee; }
      }
      const float s = (p1 + p2) + 1e-9f;
      out[t * 2 + 0] = (float)i1;
      out[t * 2 + 1] = (float)i2;
      out[2 * NTOK + t * 2 + 0] = p1 / s;
      out[2 * NTOK + t * 2 + 1] = p2 / s;
      route[t] = i1;
    }
    __syncthreads();
  }
}

// Segment-sum v2: 512 threads = 8 waves; wave owns 64 tokens, no barriers in hot loop.
// grid = 32 token-groups x 8 h-chunks. LDS f32 atomics (ds_add), conflict-free stride-1.
__global__ __launch_bounds__(512)
void segsum_kernel(const float* __restrict__ x, const int* __restrict__ route,
                   float* __restrict__ sums, int* __restrict__ counts) {
  __shared__ float ls[NEXP * 256];   // 64 KB
  __shared__ int lcnt[NEXP];
  const int tid  = threadIdx.x;
  const int lane = tid & 63;
  const int w    = tid >> 6;         // wave 0..7
  const int hc   = blockIdx.x & 7;
  const int tg   = blockIdx.x >> 3;  // 0..31
  const int hb   = hc * 256;
  #pragma unroll
  for (int i = 0; i < 32; ++i) ls[tid + i * 512] = 0.f;
  if (tid < NEXP) lcnt[tid] = 0;
  __syncthreads();
  const int tbase = tg * 512 + w * 64;
  #pragma unroll 4
  for (int i = 0; i < 64; ++i) {
    const int t = tbase + i;
    const int e = route[t];                       // wave-uniform -> scalar load
    const float* xr = x + (size_t)t * HDIM + hb + lane;
    #pragma unroll
    for (int j = 0; j < 4; ++j)
      atomicAdd(&ls[e * 256 + lane + 64 * j], xr[64 * j]);
    if (hc == 0 && lane == 0) atomicAdd(&lcnt[e], 1);
  }
  __syncthreads();
  #pragma unroll
  for (int i = tid; i < NEXP * 256; i += 512) {
    const int e = i >> 8, h = i & 255;
    atomicAdd(&sums[e * HDIM + hb + h], ls[i]);
  }
  if (hc == 0 && tid < NEXP && lcnt[tid] > 0) atomicAdd(&counts[tid], lcnt[tid]);
}

__global__ __launch_bounds__(256)
void finalize_kernel(const float* __restrict__ c, const float* __restrict__ sums,
                     const int* __restrict__ counts, float* __restrict__ out) {
  __shared__ float red[4];
  const int e = blockIdx.x;
  const int tid = threadIdx.x;
  const float cnt = (float)counts[e];
  const float minv = 1.0f / (cnt + 1e-6f);
  float u[8], cv[8];
  float ss = 0.f;
  #pragma unroll
  for (int j = 0; j < 8; ++j) {
    int h = tid + j * 256;
    cv[j] = c[e * HDIM + h];
    float mean = sums[e * HDIM + h] * minv;
    u[j] = 0.9f * cv[j] + 0.1f * mean;
    ss += u[j] * u[j];
  }
  float tot = block_reduce_sum(ss, red);
  float sc = 1.0f / fmaxf(sqrtf(tot), 1e-12f);
  const bool nz = cnt > 0.f;
  #pragma unroll
  for (int j = 0; j < 8; ++j) {
    int h = tid + j * 256;
    out[4 * NTOK + e * HDIM + h] = nz ? u[j] * sc : cv[j];
  }
}

// ---- fallback fused router (R5, known-good) for small ws ----
__global__ __launch_bounds__(256)
void router_kernel(const float* __restrict__ x, const float* __restrict__ c,
                   const float* __restrict__ inv_nc, float* __restrict__ out,
                   int* __restrict__ route, int* __restrict__ nflag,
                   int* __restrict__ flags) {
  __shared__ __align__(16) float xs[64][36];
  __shared__ float lgs[64][67];
  const int tid  = threadIdx.x;
  const int lane = tid & 63;
  const int w    = tid >> 6;
  const int t0   = blockIdx.x * 64;
  const int e0   = __builtin_amdgcn_readfirstlane(w * 16);
  const float* cb = c + (size_t)e0 * HDIM;
  const int st = tid >> 3;
  const int sk = (tid & 7) * 4;
  float acc[16];
  #pragma unroll
  for (int e = 0; e < 16; ++e) acc[e] = 0.f;
  float nacc = 0.f;
  float4 p0 = *(const float4*)&x[(size_t)(t0 + st)      * HDIM + sk];
  float4 p1 = *(const float4*)&x[(size_t)(t0 + st + 32) * HDIM + sk];
  for (int k0 = 0; k0 < HDIM; k0 += 32) {
    __syncthreads();
    *(float4*)&xs[st][sk]      = p0;
    *(float4*)&xs[st + 32][sk] = p1;
    __syncthreads();
    const int kn = k0 + 32;
    if (kn < HDIM) {
      p0 = *(const float4*)&x[(size_t)(t0 + st)      * HDIM + kn + sk];
      p1 = *(const float4*)&x[(size_t)(t0 + st + 32) * HDIM + kn + sk];
    }
    float a[32];
    #pragma unroll
    for (int j = 0; j < 32; j += 4) {
      float4 v = *(const float4*)&xs[lane][j];
      a[j] = v.x; a[j+1] = v.y; a[j+2] = v.z; a[j+3] = v.w;
    }
    if (w == 0) {
      #pragma unroll
      for (int j = 0; j < 32; ++j) nacc += a[j] * a[j];
    }
    #pragma unroll
    for (int e = 0; e < 16; ++e) {
      const float* br = cb + (size_t)e * HDIM + k0;
      #pragma unroll
      for (int j = 0; j < 32; j += 4) {
        float4 bv = *(const float4*)&br[j];
        acc[e] += a[j]*bv.x + a[j+1]*bv.y + a[j+2]*bv.z + a[j+3]*bv.w;
      }
    }
  }
  #pragma unroll
  for (int e = 0; e < 16; ++e) lgs[lane][e0 + e] = acc[e] * inv_nc[e0 + e];
  __syncthreads();
  if (w == 0) {
    const float inv_nx = 1.0f / fmaxf(sqrtf(nacc), 1e-12f);
    float m1 = -1e30f, m2 = -1e30f, m3 = -1e30f;
    int i1 = 0, i2 = 0;
    for (int e = 0; e < NEXP; ++e) {
      float l = lgs[lane][e] * inv_nx;
      if (l > m1)      { m3 = m2; m2 = m1; i2 = i1; m1 = l; i1 = e; }
      else if (l > m2) { m3 = m2; m2 = l; i2 = e; }
      else if (l > m3) { m3 = l; }
    }
    float Z = 0.f;
    for (int e = 0; e < NEXP; ++e) Z += expf(lgs[lane][e] * inv_nx - m1);
    const float p1w = 1.0f / Z;
    const float p2w = expf(m2 - m1) / Z;
    const float s   = p1w + p2w + 1e-9f;
    const int tg = t0 + lane;
    out[tg * 2 + 0] = (float)i1;
    out[tg * 2 + 1] = (float)i2;
    out[2 * NTOK + tg * 2 + 0] = p1w / s;
    out[2 * NTOK + tg * 2 + 1] = p2w / s;
    route[tg] = i1;
    if ((m1 - m2) < TAU || (m2 - m3) < TAU) {
      int idx = atomicAdd(nflag, 1);
      flags[idx] = tg;
    }
  }
}

extern "C" void kernel_launch(void* const* d_in, const int* in_sizes, int n_in,
                              void* d_out, int out_size, void* d_ws, size_t ws_size,
                              hipStream_t stream) {
  const float* x = (const float*)d_in[0];
  const float* c = (const float*)d_in[1];
  float* out = (float*)d_out;
  float* ws = (float*)d_ws;

  float* inv_nc = ws;
  int*   counts = (int*)(ws + 64);
  int*   nflag  = (int*)(ws + 128);
  int*   route  = (int*)(ws + 192);
  int*   flags  = (int*)(ws + 16576);
  float* sums   = ws + 32960;
  float* xnorm2 = ws + 164032;
  float* logits = ws + 180416;

  const size_t NEED = 1228992ull * 4ull;
  if (ws_size >= NEED) {
    zero_kernel<<<1, 256, 0, stream>>>(ws + 64, 128);                 // counts+nflag
    zero_kernel<<<4672, 256, 0, stream>>>(ws + 32960, 1196032);       // sums+xnorm2+logits
    cnorm_kernel<<<NEXP, 256, 0, stream>>>(c, inv_nc);
    gemm_kernel<<<512, 256, 0, stream>>>(x, c, logits, xnorm2);
    softmax_kernel<<<64, 256, 0, stream>>>(logits, xnorm2, inv_nc, out, route, nflag, flags);
    refine_np_kernel<<<1024, 64, 0, stream>>>(x, c, out, route, nflag, flags);
    segsum_kernel<<<256, 512, 0, stream>>>(x, route, sums, counts);
    finalize_kernel<<<NEXP, 256, 0, stream>>>(c, sums, counts, out);
  } else {
    zero_kernel<<<1, 256, 0, stream>>>(ws + 64, 128);
    zero_kernel<<<512, 256, 0, stream>>>(sums, 131072);
    cnorm_kernel<<<NEXP, 256, 0, stream>>>(c, inv_nc);
    router_kernel<<<NTOK / 64, 256, 0, stream>>>(x, c, inv_nc, out, route, nflag, flags);
    refine_np_kernel<<<1024, 64, 0, stream>>>(x, c, out, route, nflag, flags);
    segsum_kernel<<<256, 512, 0, stream>>>(x, route, sums, counts);
    finalize_kernel<<<NEXP, 256, 0, stream>>>(c, sums, counts, out);
  }
}

// Round 8
// 452.037 us; speedup vs baseline: 1.8983x; 1.3364x over previous
//
#include <hip/hip_runtime.h>
#include <math.h>

#define NTOK 16384
#define HDIM 2048
#define NEXP 64
#define KK   32
#define TAU  5e-5f
#define LGT  16384   // logits row stride (tokens), layout [e][t]

// ws layout (4-byte units):
// [0..64)              inv_nc (f32)
// [64..128)            counts (i32)
// [128..192)           nflag + pad (i32)
// [192..16576)         route  (i32)
// [16576..32960)       flags  (i32)
// [32960..164032)      sums   (f32, 64x2048)
// [164032..180416)     xnorm2 (f32, 16384)
// [180416..1228992)    logits (f32, 64x16384)
// [1228992..1360064)   bn     (f32, 64x2048)  normalized centers   total ~5.45 MB

__global__ __launch_bounds__(256)
void zero_kernel(float* p, int n) {
  int i = blockIdx.x * 256 + threadIdx.x;
  if (i < n) p[i] = 0.0f;
}

__device__ __forceinline__ float block_reduce_sum(float v, float* red) {
  #pragma unroll
  for (int o = 32; o > 0; o >>= 1) v += __shfl_down(v, o, 64);
  int lane = threadIdx.x & 63;
  int wid  = threadIdx.x >> 6;
  if (lane == 0) red[wid] = v;
  __syncthreads();
  float s = red[0] + red[1] + red[2] + red[3];
  __syncthreads();
  return s;
}

__device__ __forceinline__ double block_reduce_sum_f64(double v, double* red) {
  const int tid = threadIdx.x;
  red[tid] = v;
  __syncthreads();
  if (tid < 128) red[tid] += red[tid + 128];
  __syncthreads();
  if (tid < 64)  red[tid] += red[tid + 64];
  __syncthreads();
  double s = 0.0;
  if (tid < 64) {
    s = red[tid];
    #pragma unroll
    for (int o = 32; o > 0; o >>= 1) s += __shfl_down(s, o, 64);
  }
  if (tid == 0) red[0] = s;
  __syncthreads();
  s = red[0];
  __syncthreads();
  return s;
}

__global__ __launch_bounds__(256)
void cnorm_kernel(const float* __restrict__ c, float* __restrict__ inv_nc) {
  __shared__ float red[4];
  int e = blockIdx.x;
  float ss = 0.f;
  #pragma unroll
  for (int j = 0; j < 8; ++j) {
    float v = c[e * HDIM + threadIdx.x + j * 256];
    ss += v * v;
  }
  float tot = block_reduce_sum(ss, red);
  if (threadIdx.x == 0) inv_nc[e] = 1.0f / fmaxf(sqrtf(tot), 1e-12f);
}

// fp64 center norms -> fp32, then materialize bn[e][k] = fl32(c/nc32) (numpy's centers_n).
__global__ __launch_bounds__(256)
void cnormalize_kernel(const float* __restrict__ c, float* __restrict__ bn) {
  __shared__ double redd[256];
  __shared__ float s_nc;
  const int e = blockIdx.x;
  const int tid = threadIdx.x;
  const float* cr = c + (size_t)e * HDIM;
  double acc = 0.0;
  #pragma unroll
  for (int i = 0; i < 8; ++i) {
    double v = (double)cr[tid + 256 * i];
    acc += v * v;
  }
  double cn = block_reduce_sum_f64(acc, redd);
  if (tid == 0) s_nc = (float)fmax(sqrt(cn), 1e-12);
  __syncthreads();
  const double nc = (double)s_nc;
  #pragma unroll
  for (int i = 0; i < 8; ++i) {
    int k = tid + 256 * i;
    bn[(size_t)e * HDIM + k] = (float)((double)cr[k] / nc);
  }
}

// K-split GEMM: block = 128 tokens x 64 experts x 512 K. grid = 128 mtiles x 4 ksplits.
__global__ __launch_bounds__(256)
void gemm_kernel(const float* __restrict__ x, const float* __restrict__ c,
                 float* __restrict__ logits, float* __restrict__ xnorm2) {
  __shared__ __align__(16) float xs[KK][132];  // [k][token]; 4224 floats, reused as epilogue tile
  __shared__ __align__(16) float cs[KK][68];   // [k][expert]

  const int tid = threadIdx.x;
  const int mt  = blockIdx.x >> 2;
  const int ks  = blockIdx.x & 3;
  const int t0  = mt * 128;
  const int kb  = ks * 512;
  const int tx  = tid & 15;
  const int ty  = tid >> 4;
  const int r0  = ty * 8;
  const int e0t = tx * 4;
  const int sr = tid >> 1;
  const int sq = (tid & 1) * 16;
  const int er = tid >> 2;
  const int eq = (tid & 3) * 8;

  const float* xrow = x + (size_t)(t0 + sr) * HDIM + kb + sq;
  const float* crow = c + (size_t)er * HDIM + kb + eq;

  float4 xp[4], cp[2];
  #pragma unroll
  for (int i = 0; i < 4; ++i) xp[i] = *(const float4*)(xrow + 4 * i);
  #pragma unroll
  for (int i = 0; i < 2; ++i) cp[i] = *(const float4*)(crow + 4 * i);

  float acc[4][8];
  #pragma unroll
  for (int j = 0; j < 4; ++j)
    #pragma unroll
    for (int i = 0; i < 8; ++i) acc[j][i] = 0.f;
  float nacc = 0.f;

  for (int it = 0; it < 16; ++it) {
    __syncthreads();
    #pragma unroll
    for (int i = 0; i < 4; ++i) {
      xs[sq + 4*i + 0][sr] = xp[i].x; xs[sq + 4*i + 1][sr] = xp[i].y;
      xs[sq + 4*i + 2][sr] = xp[i].z; xs[sq + 4*i + 3][sr] = xp[i].w;
      nacc += xp[i].x*xp[i].x + xp[i].y*xp[i].y + xp[i].z*xp[i].z + xp[i].w*xp[i].w;
    }
    #pragma unroll
    for (int i = 0; i < 2; ++i) {
      cs[eq + 4*i + 0][er] = cp[i].x; cs[eq + 4*i + 1][er] = cp[i].y;
      cs[eq + 4*i + 2][er] = cp[i].z; cs[eq + 4*i + 3][er] = cp[i].w;
    }
    __syncthreads();
    if (it < 15) {
      const float* xn = xrow + (it + 1) * KK;
      const float* cn = crow + (it + 1) * KK;
      #pragma unroll
      for (int i = 0; i < 4; ++i) xp[i] = *(const float4*)(xn + 4 * i);
      #pragma unroll
      for (int i = 0; i < 2; ++i) cp[i] = *(const float4*)(cn + 4 * i);
    }
    #pragma unroll
    for (int k = 0; k < KK; ++k) {
      float4 a0 = *(const float4*)&xs[k][r0];
      float4 a1 = *(const float4*)&xs[k][r0 + 4];
      float4 b  = *(const float4*)&cs[k][e0t];
      acc[0][0] += b.x*a0.x; acc[0][1] += b.x*a0.y; acc[0][2] += b.x*a0.z; acc[0][3] += b.x*a0.w;
      acc[0][4] += b.x*a1.x; acc[0][5] += b.x*a1.y; acc[0][6] += b.x*a1.z; acc[0][7] += b.x*a1.w;
      acc[1][0] += b.y*a0.x; acc[1][1] += b.y*a0.y; acc[1][2] += b.y*a0.z; acc[1][3] += b.y*a0.w;
      acc[1][4] += b.y*a1.x; acc[1][5] += b.y*a1.y; acc[1][6] += b.y*a1.z; acc[1][7] += b.y*a1.w;
      acc[2][0] += b.z*a0.x; acc[2][1] += b.z*a0.y; acc[2][2] += b.z*a0.z; acc[2][3] += b.z*a0.w;
      acc[2][4] += b.z*a1.x; acc[2][5] += b.z*a1.y; acc[2][6] += b.z*a1.z; acc[2][7] += b.z*a1.w;
      acc[3][0] += b.w*a0.x; acc[3][1] += b.w*a0.y; acc[3][2] += b.w*a0.z; acc[3][3] += b.w*a0.w;
      acc[3][4] += b.w*a1.x; acc[3][5] += b.w*a1.y; acc[3][6] += b.w*a1.z; acc[3][7] += b.w*a1.w;
    }
  }

  atomicAdd(&xnorm2[t0 + sr], nacc);

  float* lt = &xs[0][0];   // 4224 floats >= 4096 needed
  #pragma unroll
  for (int eh = 0; eh < 2; ++eh) {
    __syncthreads();
    if ((tx >> 3) == eh) {
      const int exl = (tx & 7) * 4;
      #pragma unroll
      for (int j = 0; j < 4; ++j)
        #pragma unroll
        for (int i = 0; i < 8; ++i)
          lt[(exl + j) * 128 + r0 + i] = acc[j][i];
    }
    __syncthreads();
    #pragma unroll
    for (int n = 0; n < 16; ++n) {
      const int f = tid + n * 256;
      const int e = (f >> 7) + eh * 32;
      const int t = f & 127;
      atomicAdd(&logits[(size_t)e * LGT + t0 + t], lt[f]);
    }
  }
}

// softmax / top-2 / flag. Thread = token.
__global__ __launch_bounds__(256)
void softmax_kernel(const float* __restrict__ logits, const float* __restrict__ xnorm2,
                    const float* __restrict__ inv_nc, float* __restrict__ out,
                    int* __restrict__ route, int* __restrict__ nflag,
                    int* __restrict__ flags) {
  __shared__ float snc[NEXP];
  const int tid = threadIdx.x;
  if (tid < NEXP) snc[tid] = inv_nc[tid];
  __syncthreads();
  const int t = blockIdx.x * 256 + tid;
  const float inv_nx = 1.0f / fmaxf(sqrtf(xnorm2[t]), 1e-12f);
  float lv[NEXP];
  #pragma unroll
  for (int e = 0; e < NEXP; ++e)
    lv[e] = logits[(size_t)e * LGT + t] * snc[e] * inv_nx;
  float m1 = -1e30f, m2 = -1e30f, m3 = -1e30f;
  int i1 = 0, i2 = 0;
  #pragma unroll
  for (int e = 0; e < NEXP; ++e) {
    float l = lv[e];
    if (l > m1)      { m3 = m2; m2 = m1; i2 = i1; m1 = l; i1 = e; }
    else if (l > m2) { m3 = m2; m2 = l; i2 = e; }
    else if (l > m3) { m3 = l; }
  }
  float Z = 0.f;
  #pragma unroll
  for (int e = 0; e < NEXP; ++e) Z += expf(lv[e] - m1);
  const float p1w = 1.0f / Z;
  const float p2w = expf(m2 - m1) / Z;
  const float s   = p1w + p2w + 1e-9f;
  out[t * 2 + 0] = (float)i1;
  out[t * 2 + 1] = (float)i2;
  out[2 * NTOK + t * 2 + 0] = p1w / s;
  out[2 * NTOK + t * 2 + 1] = p2w / s;
  route[t] = i1;
  if ((m1 - m2) < TAU || (m2 - m3) < TAU) {
    int idx = atomicAdd(nflag, 1);
    flags[idx] = t;
  }
}

// Refine v2: block per flagged token; wave w -> experts [16w,16w+16), lane strides K.
// Same decision numerics as the R5/R7 passing refine (fp64 dots of fp32-normalized
// vectors, fp32 logits, fp32 exp, numpy pairwise Z, strict-> ascending top-2).
__global__ __launch_bounds__(256)
void refine_np_kernel(const float* __restrict__ x, const float* __restrict__ bn,
                      float* __restrict__ out, int* __restrict__ route,
                      const int* __restrict__ nflag, const int* __restrict__ flags) {
  __shared__ float a_lds[HDIM];
  __shared__ double redd[256];
  __shared__ float lf[NEXP];
  __shared__ float s_nx;
  const int tid  = threadIdx.x;
  const int lane = tid & 63;
  const int w    = tid >> 6;
  const int n = *nflag;
  for (int j = blockIdx.x; j < n; j += gridDim.x) {
    const int t = flags[j];
    const float* xr = x + (size_t)t * HDIM;
    double xacc = 0.0;
    #pragma unroll
    for (int i = 0; i < 8; ++i) {
      double v = (double)xr[tid + 256 * i];
      xacc += v * v;
    }
    double xn = block_reduce_sum_f64(xacc, redd);
    if (tid == 0) s_nx = (float)fmax(sqrt(xn), 1e-12);
    __syncthreads();
    const double nx = (double)s_nx;
    #pragma unroll
    for (int i = 0; i < 8; ++i) {
      int k = tid + 256 * i;
      a_lds[k] = (float)((double)xr[k] / nx);
    }
    __syncthreads();
    #pragma unroll 1
    for (int ei = 0; ei < 16; ++ei) {
      const int e = w * 16 + ei;
      const float* br = bn + (size_t)e * HDIM;
      double d = 0.0;
      #pragma unroll 8
      for (int i = 0; i < 32; ++i) {
        int k = lane + 64 * i;
        d += (double)a_lds[k] * (double)br[k];
      }
      #pragma unroll
      for (int o = 32; o > 0; o >>= 1) d += __shfl_down(d, o, 64);
      if (lane == 0) lf[e] = (float)d;
    }
    __syncthreads();
    if (tid == 0) {
      float m32 = lf[0];
      for (int ee = 1; ee < NEXP; ++ee) m32 = fmaxf(m32, lf[ee]);
      float ex[NEXP];
      for (int ee = 0; ee < NEXP; ++ee)
        ex[ee] = (float)exp((double)(lf[ee] - m32));
      float r[8];
      #pragma unroll
      for (int q = 0; q < 8; ++q) r[q] = ex[q];
      for (int i = 8; i < NEXP; i += 8)
        #pragma unroll
        for (int q = 0; q < 8; ++q) r[q] += ex[i + q];
      const float Z = ((r[0] + r[1]) + (r[2] + r[3])) + ((r[4] + r[5]) + (r[6] + r[7]));
      float p1 = -1.f, p2 = -1.f;
      int i1 = 0, i2 = 0;
      for (int ee = 0; ee < NEXP; ++ee) {
        float p = ex[ee] / Z;
        if (p > p1)      { p2 = p1; i2 = i1; p1 = p; i1 = ee; }
        else if (p > p2) { p2 = p; i2 = ee; }
      }
      const float s = (p1 + p2) + 1e-9f;
      out[t * 2 + 0] = (float)i1;
      out[t * 2 + 1] = (float)i2;
      out[2 * NTOK + t * 2 + 0] = p1 / s;
      out[2 * NTOK + t * 2 + 1] = p2 / s;
      route[t] = i1;
    }
    __syncthreads();
  }
}

// slow fallback refine (no bn dependency) for small-ws path
__global__ __launch_bounds__(64)
void refine_np_slow(const float* __restrict__ x, const float* __restrict__ c,
                    float* __restrict__ out, int* __restrict__ route,
                    const int* __restrict__ nflag, const int* __restrict__ flags) {
  __shared__ float lf[NEXP];
  const int e = threadIdx.x;
  const int n = *nflag;
  for (int j = blockIdx.x; j < n; j += gridDim.x) {
    const int t = flags[j];
    const float* xr = x + (size_t)t * HDIM;
    const float* cr = c + (size_t)e * HDIM;
    double xn = 0.0, cn = 0.0;
    for (int k = 0; k < HDIM; ++k) {
      double xv = (double)xr[k];
      double cv = (double)cr[k];
      xn += xv * xv;
      cn += cv * cv;
    }
    const float nx32 = (float)fmax(sqrt(xn), 1e-12);
    const float nc32 = (float)fmax(sqrt(cn), 1e-12);
    double d = 0.0;
    for (int k = 0; k < HDIM; ++k) {
      float a = (float)((double)xr[k] / (double)nx32);
      float b = (float)((double)cr[k] / (double)nc32);
      d += (double)a * (double)b;
    }
    lf[e] = (float)d;
    __syncthreads();
    if (e == 0) {
      float m32 = lf[0];
      for (int ee = 1; ee < NEXP; ++ee) m32 = fmaxf(m32, lf[ee]);
      float ex[NEXP];
      for (int ee = 0; ee < NEXP; ++ee)
        ex[ee] = (float)exp((double)(lf[ee] - m32));
      float r[8];
      #pragma unroll
      for (int q = 0; q < 8; ++q) r[q] = ex[q];
      for (int i = 8; i < NEXP; i += 8)
        #pragma unroll
        for (int q = 0; q < 8; ++q) r[q] += ex[i + q];
      const float Z = ((r[0] + r[1]) + (r[2] + r[3])) + ((r[4] + r[5]) + (r[6] + r[7]));
      float p1 = -1.f, p2 = -1.f;
      int i1 = 0, i2 = 0;
      for (int ee = 0; ee < NEXP; ++ee) {
        float p = ex[ee] / Z;
        if (p > p1)      { p2 = p1; i2 = i1; p1 = p; i1 = ee; }
        else if (p > p2) { p2 = p; i2 = ee; }
      }
      const float s = (p1 + p2) + 1e-9f;
      out[t * 2 + 0] = (float)i1;
      out[t * 2 + 1] = (float)i2;
      out[2 * NTOK + t * 2 + 0] = p1 / s;
      out[2 * NTOK + t * 2 + 1] = p2 / s;
      route[t] = i1;
    }
    __syncthreads();
  }
}

// Segment-sum v2: 512 threads = 8 waves; wave owns 64 tokens, no barriers in hot loop.
__global__ __launch_bounds__(512)
void segsum_kernel(const float* __restrict__ x, const int* __restrict__ route,
                   float* __restrict__ sums, int* __restrict__ counts) {
  __shared__ float ls[NEXP * 256];   // 64 KB
  __shared__ int lcnt[NEXP];
  const int tid  = threadIdx.x;
  const int lane = tid & 63;
  const int w    = tid >> 6;
  const int hc   = blockIdx.x & 7;
  const int tg   = blockIdx.x >> 3;
  const int hb   = hc * 256;
  #pragma unroll
  for (int i = 0; i < 32; ++i) ls[tid + i * 512] = 0.f;
  if (tid < NEXP) lcnt[tid] = 0;
  __syncthreads();
  const int tbase = tg * 512 + w * 64;
  #pragma unroll 4
  for (int i = 0; i < 64; ++i) {
    const int t = tbase + i;
    const int e = route[t];
    const float* xr = x + (size_t)t * HDIM + hb + lane;
    #pragma unroll
    for (int j = 0; j < 4; ++j)
      atomicAdd(&ls[e * 256 + lane + 64 * j], xr[64 * j]);
    if (hc == 0 && lane == 0) atomicAdd(&lcnt[e], 1);
  }
  __syncthreads();
  #pragma unroll
  for (int i = tid; i < NEXP * 256; i += 512) {
    const int e = i >> 8, h = i & 255;
    atomicAdd(&sums[e * HDIM + hb + h], ls[i]);
  }
  if (hc == 0 && tid < NEXP && lcnt[tid] > 0) atomicAdd(&counts[tid], lcnt[tid]);
}

__global__ __launch_bounds__(256)
void finalize_kernel(const float* __restrict__ c, const float* __restrict__ sums,
                     const int* __restrict__ counts, float* __restrict__ out) {
  __shared__ float red[4];
  const int e = blockIdx.x;
  const int tid = threadIdx.x;
  const float cnt = (float)counts[e];
  const float minv = 1.0f / (cnt + 1e-6f);
  float u[8], cv[8];
  float ss = 0.f;
  #pragma unroll
  for (int j = 0; j < 8; ++j) {
    int h = tid + j * 256;
    cv[j] = c[e * HDIM + h];
    float mean = sums[e * HDIM + h] * minv;
    u[j] = 0.9f * cv[j] + 0.1f * mean;
    ss += u[j] * u[j];
  }
  float tot = block_reduce_sum(ss, red);
  float sc = 1.0f / fmaxf(sqrtf(tot), 1e-12f);
  const bool nz = cnt > 0.f;
  #pragma unroll
  for (int j = 0; j < 8; ++j) {
    int h = tid + j * 256;
    out[4 * NTOK + e * HDIM + h] = nz ? u[j] * sc : cv[j];
  }
}

// ---- fallback fused router (R5, known-good) for small ws ----
__global__ __launch_bounds__(256)
void router_kernel(const float* __restrict__ x, const float* __restrict__ c,
                   const float* __restrict__ inv_nc, float* __restrict__ out,
                   int* __restrict__ route, int* __restrict__ nflag,
                   int* __restrict__ flags) {
  __shared__ __align__(16) float xs[64][36];
  __shared__ float lgs[64][67];
  const int tid  = threadIdx.x;
  const int lane = tid & 63;
  const int w    = tid >> 6;
  const int t0   = blockIdx.x * 64;
  const int e0   = __builtin_amdgcn_readfirstlane(w * 16);
  const float* cb = c + (size_t)e0 * HDIM;
  const int st = tid >> 3;
  const int sk = (tid & 7) * 4;
  float acc[16];
  #pragma unroll
  for (int e = 0; e < 16; ++e) acc[e] = 0.f;
  float nacc = 0.f;
  float4 p0 = *(const float4*)&x[(size_t)(t0 + st)      * HDIM + sk];
  float4 p1 = *(const float4*)&x[(size_t)(t0 + st + 32) * HDIM + sk];
  for (int k0 = 0; k0 < HDIM; k0 += 32) {
    __syncthreads();
    *(float4*)&xs[st][sk]      = p0;
    *(float4*)&xs[st + 32][sk] = p1;
    __syncthreads();
    const int kn = k0 + 32;
    if (kn < HDIM) {
      p0 = *(const float4*)&x[(size_t)(t0 + st)      * HDIM + kn + sk];
      p1 = *(const float4*)&x[(size_t)(t0 + st + 32) * HDIM + kn + sk];
    }
    float a[32];
    #pragma unroll
    for (int j = 0; j < 32; j += 4) {
      float4 v = *(const float4*)&xs[lane][j];
      a[j] = v.x; a[j+1] = v.y; a[j+2] = v.z; a[j+3] = v.w;
    }
    if (w == 0) {
      #pragma unroll
      for (int j = 0; j < 32; ++j) nacc += a[j] * a[j];
    }
    #pragma unroll
    for (int e = 0; e < 16; ++e) {
      const float* br = cb + (size_t)e * HDIM + k0;
      #pragma unroll
      for (int j = 0; j < 32; j += 4) {
        float4 bv = *(const float4*)&br[j];
        acc[e] += a[j]*bv.x + a[j+1]*bv.y + a[j+2]*bv.z + a[j+3]*bv.w;
      }
    }
  }
  #pragma unroll
  for (int e = 0; e < 16; ++e) lgs[lane][e0 + e] = acc[e] * inv_nc[e0 + e];
  __syncthreads();
  if (w == 0) {
    const float inv_nx = 1.0f / fmaxf(sqrtf(nacc), 1e-12f);
    float m1 = -1e30f, m2 = -1e30f, m3 = -1e30f;
    int i1 = 0, i2 = 0;
    for (int e = 0; e < NEXP; ++e) {
      float l = lgs[lane][e] * inv_nx;
      if (l > m1)      { m3 = m2; m2 = m1; i2 = i1; m1 = l; i1 = e; }
      else if (l > m2) { m3 = m2; m2 = l; i2 = e; }
      else if (l > m3) { m3 = l; }
    }
    float Z = 0.f;
    for (int e = 0; e < NEXP; ++e) Z += expf(lgs[lane][e] * inv_nx - m1);
    const float p1w = 1.0f / Z;
    const float p2w = expf(m2 - m1) / Z;
    const float s   = p1w + p2w + 1e-9f;
    const int tg = t0 + lane;
    out[tg * 2 + 0] = (float)i1;
    out[tg * 2 + 1] = (float)i2;
    out[2 * NTOK + tg * 2 + 0] = p1w / s;
    out[2 * NTOK + tg * 2 + 1] = p2w / s;
    route[tg] = i1;
    if ((m1 - m2) < TAU || (m2 - m3) < TAU) {
      int idx = atomicAdd(nflag, 1);
      flags[idx] = tg;
    }
  }
}

extern "C" void kernel_launch(void* const* d_in, const int* in_sizes, int n_in,
                              void* d_out, int out_size, void* d_ws, size_t ws_size,
                              hipStream_t stream) {
  const float* x = (const float*)d_in[0];
  const float* c = (const float*)d_in[1];
  float* out = (float*)d_out;
  float* ws = (float*)d_ws;

  float* inv_nc = ws;
  int*   counts = (int*)(ws + 64);
  int*   nflag  = (int*)(ws + 128);
  int*   route  = (int*)(ws + 192);
  int*   flags  = (int*)(ws + 16576);
  float* sums   = ws + 32960;
  float* xnorm2 = ws + 164032;
  float* logits = ws + 180416;
  float* bn     = ws + 1228992;

  const size_t NEED = 1360064ull * 4ull;
  if (ws_size >= NEED) {
    zero_kernel<<<1, 256, 0, stream>>>(ws + 64, 128);                 // counts+nflag
    zero_kernel<<<4672, 256, 0, stream>>>(ws + 32960, 1196032);       // sums+xnorm2+logits
    cnorm_kernel<<<NEXP, 256, 0, stream>>>(c, inv_nc);
    cnormalize_kernel<<<NEXP, 256, 0, stream>>>(c, bn);
    gemm_kernel<<<512, 256, 0, stream>>>(x, c, logits, xnorm2);
    softmax_kernel<<<64, 256, 0, stream>>>(logits, xnorm2, inv_nc, out, route, nflag, flags);
    refine_np_kernel<<<512, 256, 0, stream>>>(x, bn, out, route, nflag, flags);
    segsum_kernel<<<256, 512, 0, stream>>>(x, route, sums, counts);
    finalize_kernel<<<NEXP, 256, 0, stream>>>(c, sums, counts, out);
  } else {
    zero_kernel<<<1, 256, 0, stream>>>(ws + 64, 128);
    zero_kernel<<<512, 256, 0, stream>>>(sums, 131072);
    cnorm_kernel<<<NEXP, 256, 0, stream>>>(c, inv_nc);
    router_kernel<<<NTOK / 64, 256, 0, stream>>>(x, c, inv_nc, out, route, nflag, flags);
    refine_np_slow<<<1024, 64, 0, stream>>>(x, c, out, route, nflag, flags);
    segsum_kernel<<<256, 512, 0, stream>>>(x, route, sums, counts);
    finalize_kernel<<<NEXP, 256, 0, stream>>>(c, sums, counts, out);
  }
}

// Round 9
// 321.985 us; speedup vs baseline: 2.6651x; 1.4039x over previous
//
#include <hip/hip_runtime.h>
#include <math.h>

#define NTOK 16384
#define HDIM 2048
#define NEXP 64
#define KK   32
#define TAU  5e-5f
#define LGT  16384   // logits row stride (tokens), layout [e][t]
#define MAXB 2048    // bucket capacity per expert (mean 256, 112 sigma margin)

// ws layout (4-byte units):
// [0..64)              inv_nc (f32)
// [64..128)            counts/cursor (i32)
// [128..192)           nflag + pad (i32)
// [192..16576)         route  (i32)
// [16576..32960)       flags  (i32)
// [32960..164032)      sums   (f32, 64x2048)
// [164032..180416)     xnorm2 (f32, 16384)
// [180416..1228992)    logits (f32, 64x16384)
// [1228992..1360064)   bn     (f32, 64x2048)
// [1360064..1491136)   bucket (i32, 64x2048)    total ~5.96 MB

__global__ __launch_bounds__(256)
void zero_kernel(float* p, int n) {
  int i = blockIdx.x * 256 + threadIdx.x;
  if (i < n) p[i] = 0.0f;
}

__device__ __forceinline__ float block_reduce_sum(float v, float* red) {
  #pragma unroll
  for (int o = 32; o > 0; o >>= 1) v += __shfl_down(v, o, 64);
  int lane = threadIdx.x & 63;
  int wid  = threadIdx.x >> 6;
  if (lane == 0) red[wid] = v;
  __syncthreads();
  float s = red[0] + red[1] + red[2] + red[3];
  __syncthreads();
  return s;
}

__device__ __forceinline__ double block_reduce_sum_f64(double v, double* red) {
  const int tid = threadIdx.x;
  red[tid] = v;
  __syncthreads();
  if (tid < 128) red[tid] += red[tid + 128];
  __syncthreads();
  if (tid < 64)  red[tid] += red[tid + 64];
  __syncthreads();
  double s = 0.0;
  if (tid < 64) {
    s = red[tid];
    #pragma unroll
    for (int o = 32; o > 0; o >>= 1) s += __shfl_down(s, o, 64);
  }
  if (tid == 0) red[0] = s;
  __syncthreads();
  s = red[0];
  __syncthreads();
  return s;
}

__global__ __launch_bounds__(256)
void cnorm_kernel(const float* __restrict__ c, float* __restrict__ inv_nc) {
  __shared__ float red[4];
  int e = blockIdx.x;
  float ss = 0.f;
  #pragma unroll
  for (int j = 0; j < 8; ++j) {
    float v = c[e * HDIM + threadIdx.x + j * 256];
    ss += v * v;
  }
  float tot = block_reduce_sum(ss, red);
  if (threadIdx.x == 0) inv_nc[e] = 1.0f / fmaxf(sqrtf(tot), 1e-12f);
}

// fp64 center norms -> fp32, materialize bn[e][k] = fl32(c/nc32) (numpy's centers_n).
__global__ __launch_bounds__(256)
void cnormalize_kernel(const float* __restrict__ c, float* __restrict__ bn) {
  __shared__ double redd[256];
  __shared__ float s_nc;
  const int e = blockIdx.x;
  const int tid = threadIdx.x;
  const float* cr = c + (size_t)e * HDIM;
  double acc = 0.0;
  #pragma unroll
  for (int i = 0; i < 8; ++i) {
    double v = (double)cr[tid + 256 * i];
    acc += v * v;
  }
  double cn = block_reduce_sum_f64(acc, redd);
  if (tid == 0) s_nc = (float)fmax(sqrt(cn), 1e-12);
  __syncthreads();
  const double nc = (double)s_nc;
  #pragma unroll
  for (int i = 0; i < 8; ++i) {
    int k = tid + 256 * i;
    bn[(size_t)e * HDIM + k] = (float)((double)cr[k] / nc);
  }
}

// K-split GEMM: block = 128 tokens x 64 experts x 512 K. grid = 128 mtiles x 4 ksplits.
__global__ __launch_bounds__(256)
void gemm_kernel(const float* __restrict__ x, const float* __restrict__ c,
                 float* __restrict__ logits, float* __restrict__ xnorm2) {
  __shared__ __align__(16) float xs[KK][132];  // 4224 floats, reused as epilogue tile
  __shared__ __align__(16) float cs[KK][68];

  const int tid = threadIdx.x;
  const int mt  = blockIdx.x >> 2;
  const int ks  = blockIdx.x & 3;
  const int t0  = mt * 128;
  const int kb  = ks * 512;
  const int tx  = tid & 15;
  const int ty  = tid >> 4;
  const int r0  = ty * 8;
  const int e0t = tx * 4;
  const int sr = tid >> 1;
  const int sq = (tid & 1) * 16;
  const int er = tid >> 2;
  const int eq = (tid & 3) * 8;

  const float* xrow = x + (size_t)(t0 + sr) * HDIM + kb + sq;
  const float* crow = c + (size_t)er * HDIM + kb + eq;

  float4 xp[4], cp[2];
  #pragma unroll
  for (int i = 0; i < 4; ++i) xp[i] = *(const float4*)(xrow + 4 * i);
  #pragma unroll
  for (int i = 0; i < 2; ++i) cp[i] = *(const float4*)(crow + 4 * i);

  float acc[4][8];
  #pragma unroll
  for (int j = 0; j < 4; ++j)
    #pragma unroll
    for (int i = 0; i < 8; ++i) acc[j][i] = 0.f;
  float nacc = 0.f;

  for (int it = 0; it < 16; ++it) {
    __syncthreads();
    #pragma unroll
    for (int i = 0; i < 4; ++i) {
      xs[sq + 4*i + 0][sr] = xp[i].x; xs[sq + 4*i + 1][sr] = xp[i].y;
      xs[sq + 4*i + 2][sr] = xp[i].z; xs[sq + 4*i + 3][sr] = xp[i].w;
      nacc += xp[i].x*xp[i].x + xp[i].y*xp[i].y + xp[i].z*xp[i].z + xp[i].w*xp[i].w;
    }
    #pragma unroll
    for (int i = 0; i < 2; ++i) {
      cs[eq + 4*i + 0][er] = cp[i].x; cs[eq + 4*i + 1][er] = cp[i].y;
      cs[eq + 4*i + 2][er] = cp[i].z; cs[eq + 4*i + 3][er] = cp[i].w;
    }
    __syncthreads();
    if (it < 15) {
      const float* xn = xrow + (it + 1) * KK;
      const float* cn = crow + (it + 1) * KK;
      #pragma unroll
      for (int i = 0; i < 4; ++i) xp[i] = *(const float4*)(xn + 4 * i);
      #pragma unroll
      for (int i = 0; i < 2; ++i) cp[i] = *(const float4*)(cn + 4 * i);
    }
    #pragma unroll
    for (int k = 0; k < KK; ++k) {
      float4 a0 = *(const float4*)&xs[k][r0];
      float4 a1 = *(const float4*)&xs[k][r0 + 4];
      float4 b  = *(const float4*)&cs[k][e0t];
      acc[0][0] += b.x*a0.x; acc[0][1] += b.x*a0.y; acc[0][2] += b.x*a0.z; acc[0][3] += b.x*a0.w;
      acc[0][4] += b.x*a1.x; acc[0][5] += b.x*a1.y; acc[0][6] += b.x*a1.z; acc[0][7] += b.x*a1.w;
      acc[1][0] += b.y*a0.x; acc[1][1] += b.y*a0.y; acc[1][2] += b.y*a0.z; acc[1][3] += b.y*a0.w;
      acc[1][4] += b.y*a1.x; acc[1][5] += b.y*a1.y; acc[1][6] += b.y*a1.z; acc[1][7] += b.y*a1.w;
      acc[2][0] += b.z*a0.x; acc[2][1] += b.z*a0.y; acc[2][2] += b.z*a0.z; acc[2][3] += b.z*a0.w;
      acc[2][4] += b.z*a1.x; acc[2][5] += b.z*a1.y; acc[2][6] += b.z*a1.z; acc[2][7] += b.z*a1.w;
      acc[3][0] += b.w*a0.x; acc[3][1] += b.w*a0.y; acc[3][2] += b.w*a0.z; acc[3][3] += b.w*a0.w;
      acc[3][4] += b.w*a1.x; acc[3][5] += b.w*a1.y; acc[3][6] += b.w*a1.z; acc[3][7] += b.w*a1.w;
    }
  }

  atomicAdd(&xnorm2[t0 + sr], nacc);

  float* lt = &xs[0][0];   // 4224 floats >= 4096 needed
  #pragma unroll
  for (int eh = 0; eh < 2; ++eh) {
    __syncthreads();
    if ((tx >> 3) == eh) {
      const int exl = (tx & 7) * 4;
      #pragma unroll
      for (int j = 0; j < 4; ++j)
        #pragma unroll
        for (int i = 0; i < 8; ++i)
          lt[(exl + j) * 128 + r0 + i] = acc[j][i];
    }
    __syncthreads();
    #pragma unroll
    for (int n = 0; n < 16; ++n) {
      const int f = tid + n * 256;
      const int e = (f >> 7) + eh * 32;
      const int t = f & 127;
      atomicAdd(&logits[(size_t)e * LGT + t0 + t], lt[f]);
    }
  }
}

// softmax / top-2 / flag. Thread = token.
__global__ __launch_bounds__(256)
void softmax_kernel(const float* __restrict__ logits, const float* __restrict__ xnorm2,
                    const float* __restrict__ inv_nc, float* __restrict__ out,
                    int* __restrict__ route, int* __restrict__ nflag,
                    int* __restrict__ flags) {
  __shared__ float snc[NEXP];
  const int tid = threadIdx.x;
  if (tid < NEXP) snc[tid] = inv_nc[tid];
  __syncthreads();
  const int t = blockIdx.x * 256 + tid;
  const float inv_nx = 1.0f / fmaxf(sqrtf(xnorm2[t]), 1e-12f);
  float lv[NEXP];
  #pragma unroll
  for (int e = 0; e < NEXP; ++e)
    lv[e] = logits[(size_t)e * LGT + t] * snc[e] * inv_nx;
  float m1 = -1e30f, m2 = -1e30f, m3 = -1e30f;
  int i1 = 0, i2 = 0;
  #pragma unroll
  for (int e = 0; e < NEXP; ++e) {
    float l = lv[e];
    if (l > m1)      { m3 = m2; m2 = m1; i2 = i1; m1 = l; i1 = e; }
    else if (l > m2) { m3 = m2; m2 = l; i2 = e; }
    else if (l > m3) { m3 = l; }
  }
  float Z = 0.f;
  #pragma unroll
  for (int e = 0; e < NEXP; ++e) Z += expf(lv[e] - m1);
  const float p1w = 1.0f / Z;
  const float p2w = expf(m2 - m1) / Z;
  const float s   = p1w + p2w + 1e-9f;
  out[t * 2 + 0] = (float)i1;
  out[t * 2 + 1] = (float)i2;
  out[2 * NTOK + t * 2 + 0] = p1w / s;
  out[2 * NTOK + t * 2 + 1] = p2w / s;
  route[t] = i1;
  if ((m1 - m2) < TAU || (m2 - m3) < TAU) {
    int idx = atomicAdd(nflag, 1);
    flags[idx] = t;
  }
}

// Refine v2 (R8, known-good): block per flagged token.
__global__ __launch_bounds__(256)
void refine_np_kernel(const float* __restrict__ x, const float* __restrict__ bn,
                      float* __restrict__ out, int* __restrict__ route,
                      const int* __restrict__ nflag, const int* __restrict__ flags) {
  __shared__ float a_lds[HDIM];
  __shared__ double redd[256];
  __shared__ float lf[NEXP];
  __shared__ float s_nx;
  const int tid  = threadIdx.x;
  const int lane = tid & 63;
  const int w    = tid >> 6;
  const int n = *nflag;
  for (int j = blockIdx.x; j < n; j += gridDim.x) {
    const int t = flags[j];
    const float* xr = x + (size_t)t * HDIM;
    double xacc = 0.0;
    #pragma unroll
    for (int i = 0; i < 8; ++i) {
      double v = (double)xr[tid + 256 * i];
      xacc += v * v;
    }
    double xn = block_reduce_sum_f64(xacc, redd);
    if (tid == 0) s_nx = (float)fmax(sqrt(xn), 1e-12);
    __syncthreads();
    const double nx = (double)s_nx;
    #pragma unroll
    for (int i = 0; i < 8; ++i) {
      int k = tid + 256 * i;
      a_lds[k] = (float)((double)xr[k] / nx);
    }
    __syncthreads();
    #pragma unroll 1
    for (int ei = 0; ei < 16; ++ei) {
      const int e = w * 16 + ei;
      const float* br = bn + (size_t)e * HDIM;
      double d = 0.0;
      #pragma unroll 8
      for (int i = 0; i < 32; ++i) {
        int k = lane + 64 * i;
        d += (double)a_lds[k] * (double)br[k];
      }
      #pragma unroll
      for (int o = 32; o > 0; o >>= 1) d += __shfl_down(d, o, 64);
      if (lane == 0) lf[e] = (float)d;
    }
    __syncthreads();
    if (tid == 0) {
      float m32 = lf[0];
      for (int ee = 1; ee < NEXP; ++ee) m32 = fmaxf(m32, lf[ee]);
      float ex[NEXP];
      for (int ee = 0; ee < NEXP; ++ee)
        ex[ee] = (float)exp((double)(lf[ee] - m32));
      float r[8];
      #pragma unroll
      for (int q = 0; q < 8; ++q) r[q] = ex[q];
      for (int i = 8; i < NEXP; i += 8)
        #pragma unroll
        for (int q = 0; q < 8; ++q) r[q] += ex[i + q];
      const float Z = ((r[0] + r[1]) + (r[2] + r[3])) + ((r[4] + r[5]) + (r[6] + r[7]));
      float p1 = -1.f, p2 = -1.f;
      int i1 = 0, i2 = 0;
      for (int ee = 0; ee < NEXP; ++ee) {
        float p = ex[ee] / Z;
        if (p > p1)      { p2 = p1; i2 = i1; p1 = p; i1 = ee; }
        else if (p > p2) { p2 = p; i2 = ee; }
      }
      const float s = (p1 + p2) + 1e-9f;
      out[t * 2 + 0] = (float)i1;
      out[t * 2 + 1] = (float)i2;
      out[2 * NTOK + t * 2 + 0] = p1 / s;
      out[2 * NTOK + t * 2 + 1] = p2 / s;
      route[t] = i1;
    }
    __syncthreads();
  }
}

// slow fallback refine (no bn dependency) for small-ws path
__global__ __launch_bounds__(64)
void refine_np_slow(const float* __restrict__ x, const float* __restrict__ c,
                    float* __restrict__ out, int* __restrict__ route,
                    const int* __restrict__ nflag, const int* __restrict__ flags) {
  __shared__ float lf[NEXP];
  const int e = threadIdx.x;
  const int n = *nflag;
  for (int j = blockIdx.x; j < n; j += gridDim.x) {
    const int t = flags[j];
    const float* xr = x + (size_t)t * HDIM;
    const float* cr = c + (size_t)e * HDIM;
    double xn = 0.0, cn = 0.0;
    for (int k = 0; k < HDIM; ++k) {
      double xv = (double)xr[k];
      double cv = (double)cr[k];
      xn += xv * xv;
      cn += cv * cv;
    }
    const float nx32 = (float)fmax(sqrt(xn), 1e-12);
    const float nc32 = (float)fmax(sqrt(cn), 1e-12);
    double d = 0.0;
    for (int k = 0; k < HDIM; ++k) {
      float a = (float)((double)xr[k] / (double)nx32);
      float b = (float)((double)cr[k] / (double)nc32);
      d += (double)a * (double)b;
    }
    lf[e] = (float)d;
    __syncthreads();
    if (e == 0) {
      float m32 = lf[0];
      for (int ee = 1; ee < NEXP; ++ee) m32 = fmaxf(m32, lf[ee]);
      float ex[NEXP];
      for (int ee = 0; ee < NEXP; ++ee)
        ex[ee] = (float)exp((double)(lf[ee] - m32));
      float r[8];
      #pragma unroll
      for (int q = 0; q < 8; ++q) r[q] = ex[q];
      for (int i = 8; i < NEXP; i += 8)
        #pragma unroll
        for (int q = 0; q < 8; ++q) r[q] += ex[i + q];
      const float Z = ((r[0] + r[1]) + (r[2] + r[3])) + ((r[4] + r[5]) + (r[6] + r[7]));
      float p1 = -1.f, p2 = -1.f;
      int i1 = 0, i2 = 0;
      for (int ee = 0; ee < NEXP; ++ee) {
        float p = ex[ee] / Z;
        if (p > p1)      { p2 = p1; i2 = i1; p1 = p; i1 = ee; }
        else if (p > p2) { p2 = p; i2 = ee; }
      }
      const float s = (p1 + p2) + 1e-9f;
      out[t * 2 + 0] = (float)i1;
      out[t * 2 + 1] = (float)i2;
      out[2 * NTOK + t * 2 + 0] = p1 / s;
      out[2 * NTOK + t * 2 + 1] = p2 / s;
      route[t] = i1;
    }
    __syncthreads();
  }
}

// Bucket scatter: cursor[e] counts tokens (== counts), bucket[e][pos] = t.
__global__ __launch_bounds__(256)
void scatter_kernel(const int* __restrict__ route, int* __restrict__ cursor,
                    int* __restrict__ bucket) {
  const int t = blockIdx.x * 256 + threadIdx.x;
  const int e = route[t];
  const int pos = atomicAdd(&cursor[e], 1);
  if (pos < MAXB) bucket[e * MAXB + pos] = t;
}

// Dense per-expert sum: block = (expert, h-chunk). No atomics, direct store.
__global__ __launch_bounds__(256)
void segsum_dense(const float* __restrict__ x, const int* __restrict__ cursor,
                  const int* __restrict__ bucket, float* __restrict__ sums) {
  __shared__ int ts[MAXB];
  const int e   = blockIdx.x >> 3;
  const int hc  = blockIdx.x & 7;
  const int hb  = hc * 256;
  const int tid = threadIdx.x;
  int n = cursor[e];
  if (n > MAXB) n = MAXB;
  for (int i = tid; i < n; i += 256) ts[i] = bucket[e * MAXB + i];
  __syncthreads();
  float a[8];
  #pragma unroll
  for (int q = 0; q < 8; ++q) a[q] = 0.f;
  int i = 0;
  for (; i + 7 < n; i += 8) {
    #pragma unroll
    for (int q = 0; q < 8; ++q)
      a[q] += x[(size_t)ts[i + q] * HDIM + hb + tid];
  }
  for (; i < n; ++i) a[0] += x[(size_t)ts[i] * HDIM + hb + tid];
  const float s = ((a[0] + a[1]) + (a[2] + a[3])) + ((a[4] + a[5]) + (a[6] + a[7]));
  sums[e * HDIM + hb + tid] = s;
}

__global__ __launch_bounds__(256)
void finalize_kernel(const float* __restrict__ c, const float* __restrict__ sums,
                     const int* __restrict__ counts, float* __restrict__ out) {
  __shared__ float red[4];
  const int e = blockIdx.x;
  const int tid = threadIdx.x;
  const float cnt = (float)counts[e];
  const float minv = 1.0f / (cnt + 1e-6f);
  float u[8], cv[8];
  float ss = 0.f;
  #pragma unroll
  for (int j = 0; j < 8; ++j) {
    int h = tid + j * 256;
    cv[j] = c[e * HDIM + h];
    float mean = sums[e * HDIM + h] * minv;
    u[j] = 0.9f * cv[j] + 0.1f * mean;
    ss += u[j] * u[j];
  }
  float tot = block_reduce_sum(ss, red);
  float sc = 1.0f / fmaxf(sqrtf(tot), 1e-12f);
  const bool nz = cnt > 0.f;
  #pragma unroll
  for (int j = 0; j < 8; ++j) {
    int h = tid + j * 256;
    out[4 * NTOK + e * HDIM + h] = nz ? u[j] * sc : cv[j];
  }
}

// ---- fallback path kernels (small ws): R5 router + old segsum ----
__global__ __launch_bounds__(256)
void router_kernel(const float* __restrict__ x, const float* __restrict__ c,
                   const float* __restrict__ inv_nc, float* __restrict__ out,
                   int* __restrict__ route, int* __restrict__ nflag,
                   int* __restrict__ flags) {
  __shared__ __align__(16) float xs[64][36];
  __shared__ float lgs[64][67];
  const int tid  = threadIdx.x;
  const int lane = tid & 63;
  const int w    = tid >> 6;
  const int t0   = blockIdx.x * 64;
  const int e0   = __builtin_amdgcn_readfirstlane(w * 16);
  const float* cb = c + (size_t)e0 * HDIM;
  const int st = tid >> 3;
  const int sk = (tid & 7) * 4;
  float acc[16];
  #pragma unroll
  for (int e = 0; e < 16; ++e) acc[e] = 0.f;
  float nacc = 0.f;
  float4 p0 = *(const float4*)&x[(size_t)(t0 + st)      * HDIM + sk];
  float4 p1 = *(const float4*)&x[(size_t)(t0 + st + 32) * HDIM + sk];
  for (int k0 = 0; k0 < HDIM; k0 += 32) {
    __syncthreads();
    *(float4*)&xs[st][sk]      = p0;
    *(float4*)&xs[st + 32][sk] = p1;
    __syncthreads();
    const int kn = k0 + 32;
    if (kn < HDIM) {
      p0 = *(const float4*)&x[(size_t)(t0 + st)      * HDIM + kn + sk];
      p1 = *(const float4*)&x[(size_t)(t0 + st + 32) * HDIM + kn + sk];
    }
    float a[32];
    #pragma unroll
    for (int j = 0; j < 32; j += 4) {
      float4 v = *(const float4*)&xs[lane][j];
      a[j] = v.x; a[j+1] = v.y; a[j+2] = v.z; a[j+3] = v.w;
    }
    if (w == 0) {
      #pragma unroll
      for (int j = 0; j < 32; ++j) nacc += a[j] * a[j];
    }
    #pragma unroll
    for (int e = 0; e < 16; ++e) {
      const float* br = cb + (size_t)e * HDIM + k0;
      #pragma unroll
      for (int j = 0; j < 32; j += 4) {
        float4 bv = *(const float4*)&br[j];
        acc[e] += a[j]*bv.x + a[j+1]*bv.y + a[j+2]*bv.z + a[j+3]*bv.w;
      }
    }
  }
  #pragma unroll
  for (int e = 0; e < 16; ++e) lgs[lane][e0 + e] = acc[e] * inv_nc[e0 + e];
  __syncthreads();
  if (w == 0) {
    const float inv_nx = 1.0f / fmaxf(sqrtf(nacc), 1e-12f);
    float m1 = -1e30f, m2 = -1e30f, m3 = -1e30f;
    int i1 = 0, i2 = 0;
    for (int e = 0; e < NEXP; ++e) {
      float l = lgs[lane][e] * inv_nx;
      if (l > m1)      { m3 = m2; m2 = m1; i2 = i1; m1 = l; i1 = e; }
      else if (l > m2) { m3 = m2; m2 = l; i2 = e; }
      else if (l > m3) { m3 = l; }
    }
    float Z = 0.f;
    for (int e = 0; e < NEXP; ++e) Z += expf(lgs[lane][e] * inv_nx - m1);
    const float p1w = 1.0f / Z;
    const float p2w = expf(m2 - m1) / Z;
    const float s   = p1w + p2w + 1e-9f;
    const int tg = t0 + lane;
    out[tg * 2 + 0] = (float)i1;
    out[tg * 2 + 1] = (float)i2;
    out[2 * NTOK + tg * 2 + 0] = p1w / s;
    out[2 * NTOK + tg * 2 + 1] = p2w / s;
    route[tg] = i1;
    if ((m1 - m2) < TAU || (m2 - m3) < TAU) {
      int idx = atomicAdd(nflag, 1);
      flags[idx] = tg;
    }
  }
}

__global__ __launch_bounds__(512)
void segsum_kernel(const float* __restrict__ x, const int* __restrict__ route,
                   float* __restrict__ sums, int* __restrict__ counts) {
  __shared__ float ls[NEXP * 256];
  __shared__ int lcnt[NEXP];
  const int tid  = threadIdx.x;
  const int lane = tid & 63;
  const int w    = tid >> 6;
  const int hc   = blockIdx.x & 7;
  const int tg   = blockIdx.x >> 3;
  const int hb   = hc * 256;
  #pragma unroll
  for (int i = 0; i < 32; ++i) ls[tid + i * 512] = 0.f;
  if (tid < NEXP) lcnt[tid] = 0;
  __syncthreads();
  const int tbase = tg * 512 + w * 64;
  #pragma unroll 4
  for (int i = 0; i < 64; ++i) {
    const int t = tbase + i;
    const int e = route[t];
    const float* xr = x + (size_t)t * HDIM + hb + lane;
    #pragma unroll
    for (int j = 0; j < 4; ++j)
      atomicAdd(&ls[e * 256 + lane + 64 * j], xr[64 * j]);
    if (hc == 0 && lane == 0) atomicAdd(&lcnt[e], 1);
  }
  __syncthreads();
  #pragma unroll
  for (int i = tid; i < NEXP * 256; i += 512) {
    const int e = i >> 8, h = i & 255;
    atomicAdd(&sums[e * HDIM + hb + h], ls[i]);
  }
  if (hc == 0 && tid < NEXP && lcnt[tid] > 0) atomicAdd(&counts[tid], lcnt[tid]);
}

extern "C" void kernel_launch(void* const* d_in, const int* in_sizes, int n_in,
                              void* d_out, int out_size, void* d_ws, size_t ws_size,
                              hipStream_t stream) {
  const float* x = (const float*)d_in[0];
  const float* c = (const float*)d_in[1];
  float* out = (float*)d_out;
  float* ws = (float*)d_ws;

  float* inv_nc = ws;
  int*   counts = (int*)(ws + 64);      // == cursor
  int*   nflag  = (int*)(ws + 128);
  int*   route  = (int*)(ws + 192);
  int*   flags  = (int*)(ws + 16576);
  float* sums   = ws + 32960;
  float* xnorm2 = ws + 164032;
  float* logits = ws + 180416;
  float* bn     = ws + 1228992;
  int*   bucket = (int*)(ws + 1360064);

  const size_t NEED = 1491136ull * 4ull;
  if (ws_size >= NEED) {
    zero_kernel<<<1, 256, 0, stream>>>(ws + 64, 128);                 // cursor+nflag
    zero_kernel<<<4160, 256, 0, stream>>>(ws + 164032, 1064960);      // xnorm2+logits
    cnorm_kernel<<<NEXP, 256, 0, stream>>>(c, inv_nc);
    cnormalize_kernel<<<NEXP, 256, 0, stream>>>(c, bn);
    gemm_kernel<<<512, 256, 0, stream>>>(x, c, logits, xnorm2);
    softmax_kernel<<<64, 256, 0, stream>>>(logits, xnorm2, inv_nc, out, route, nflag, flags);
    refine_np_kernel<<<512, 256, 0, stream>>>(x, bn, out, route, nflag, flags);
    scatter_kernel<<<64, 256, 0, stream>>>(route, counts, bucket);
    segsum_dense<<<512, 256, 0, stream>>>(x, counts, bucket, sums);
    finalize_kernel<<<NEXP, 256, 0, stream>>>(c, sums, counts, out);
  } else {
    zero_kernel<<<1, 256, 0, stream>>>(ws + 64, 128);
    zero_kernel<<<512, 256, 0, stream>>>(sums, 131072);
    cnorm_kernel<<<NEXP, 256, 0, stream>>>(c, inv_nc);
    router_kernel<<<NTOK / 64, 256, 0, stream>>>(x, c, inv_nc, out, route, nflag, flags);
    refine_np_slow<<<1024, 64, 0, stream>>>(x, c, out, route, nflag, flags);
    segsum_kernel<<<256, 512, 0, stream>>>(x, route, sums, counts);
    finalize_kernel<<<NEXP, 256, 0, stream>>>(c, sums, counts, out);
  }
}